// Round 11
// baseline (1654.292 us; speedup 1.0000x reference)
//
#include <hip/hip_runtime.h>

#define F 128

typedef __attribute__((ext_vector_type(8))) short bf16x8;
typedef __attribute__((ext_vector_type(4))) float f32x4;

// ---------------- graph build ----------------

__global__ __launch_bounds__(256) void count2_kernel(const int* __restrict__ src,
                                                     const int* __restrict__ dst,
                                                     int* __restrict__ cntd,
                                                     int* __restrict__ cnts, int e) {
    int i = blockIdx.x * 256 + threadIdx.x;
    if (i < e) {
        atomicAdd(&cntd[dst[i]], 1);
        atomicAdd(&cnts[src[i]], 1);
    }
}

__global__ __launch_bounds__(256) void dinv_kernel(const int* __restrict__ cnt,
                                                   float* __restrict__ dinv, int n) {
    int i = blockIdx.x * 256 + threadIdx.x;
    if (i < n) dinv[i] = rsqrtf((float)(cnt[i] + 1));  // +1 self loop
}

__global__ __launch_bounds__(1024) void scan_kernel(const int* __restrict__ cnt,
                                                    int* __restrict__ offs, int n) {
    __shared__ int sm[1024];
    int tid = threadIdx.x;
    int chunk = (n + 1023) >> 10;
    int b = tid * chunk;
    int e = b + chunk; if (e > n) e = n;
    int s = 0;
    for (int i = b; i < e; i++) s += cnt[i];
    sm[tid] = s;
    __syncthreads();
    for (int d = 1; d < 1024; d <<= 1) {
        int v = 0;
        if (tid >= d) v = sm[tid - d];
        __syncthreads();
        if (tid >= d) sm[tid] += v;
        __syncthreads();
    }
    int run = (tid == 0) ? 0 : sm[tid - 1];
    for (int i = b; i < e; i++) { offs[i] = run; run += cnt[i]; }
    if (tid == 1023) offs[n] = sm[1023];
}

// CSC: for each src (sequential), list of (dst, norm)
__global__ __launch_bounds__(256) void fillc_kernel(const int* __restrict__ src,
                                                    const int* __restrict__ dst,
                                                    const int* __restrict__ soffs,
                                                    int* __restrict__ curs,
                                                    const float* __restrict__ dinv,
                                                    int2* __restrict__ csc, int e) {
    int i = blockIdx.x * 256 + threadIdx.x;
    if (i >= e) return;
    int s = src[i], d = dst[i];
    int cpos = soffs[s] + atomicAdd(&curs[s], 1);
    csc[cpos] = make_int2(d, __float_as_int(dinv[s] * dinv[d]));
}

// ---------------- bf16 helpers ----------------

__device__ __forceinline__ unsigned short f32_to_bf16_rne(float x) {
    unsigned u = __float_as_uint(x);
    unsigned r = (u + 0x7fffu + ((u >> 16) & 1u)) >> 16;   // round to nearest even
    return (unsigned short)r;
}

__device__ __forceinline__ float bfhi(unsigned v) { return __uint_as_float(v & 0xffff0000u); }
__device__ __forceinline__ float bflo(unsigned v) { return __uint_as_float(v << 16); }

// ---------------- converts ----------------

__global__ __launch_bounds__(256) void cvtx_kernel(const float4* __restrict__ x4,
                                                   ushort4* __restrict__ xb4, long n4) {
    long stride = (long)gridDim.x * 256;
    for (long i = blockIdx.x * 256 + threadIdx.x; i < n4; i += stride) {
        float4 v = x4[i];
        ushort4 o;
        o.x = f32_to_bf16_rne(v.x);
        o.y = f32_to_bf16_rne(v.y);
        o.z = f32_to_bf16_rne(v.z);
        o.w = f32_to_bf16_rne(v.w);
        xb4[i] = o;
    }
}

// Wt[c][k] = bf16(W[k][c])
__global__ __launch_bounds__(128) void cvtw_kernel(const float* __restrict__ W,
                                                   unsigned short* __restrict__ Wt) {
    int c = blockIdx.x, k = threadIdx.x;
    Wt[c * F + k] = f32_to_bf16_rne(W[k * F + c]);
}

// ---------------- MFMA GEMM: outb[n][128](bf16) = hb[n][128](bf16) @ W ----------------

__global__ __launch_bounds__(256) void gemm_mfma(const unsigned short* __restrict__ hb,
                                                 const unsigned short* __restrict__ Wt,
                                                 unsigned short* __restrict__ outb, int n) {
    __shared__ unsigned short sm[4][16][F];
    const int tid = threadIdx.x;
    const int w = tid >> 6, lane = tid & 63;
    const int r = lane & 15, kg = lane >> 4;
    const long base = (long)blockIdx.x * 64 + w * 16;

    int arow = (int)(base + r);
    if (arow >= n) arow = n - 1;
    const bf16x8* __restrict__ arowp = (const bf16x8*)(hb + (size_t)arow * F);

    f32x4 acc[8] = {};
    #pragma unroll
    for (int c = 0; c < 4; c++) {
        bf16x8 a = arowp[c * 4 + kg];
        #pragma unroll
        for (int t = 0; t < 8; t++) {
            bf16x8 b = *(const bf16x8*)(Wt + (size_t)(t * 16 + r) * F + c * 32 + kg * 8);
            acc[t] = __builtin_amdgcn_mfma_f32_16x16x32_bf16(a, b, acc[t], 0, 0, 0);
        }
    }

    #pragma unroll
    for (int t = 0; t < 8; t++)
        #pragma unroll
        for (int j = 0; j < 4; j++)
            sm[w][kg * 4 + j][t * 16 + r] = f32_to_bf16_rne(acc[t][j]);
    #pragma unroll
    for (int it = 0; it < 4; it++) {
        int row = it * 4 + kg;
        long grow = base + row;
        if (grow < n) {
            uint4 v = *(uint4*)&sm[w][row][r * 8];
            *(uint4*)(outb + (size_t)grow * F + r * 8) = v;
        }
    }
}

// ---------------- Phase A: streaming src-row read + packed-bf16 atomic scatter ----------

__global__ __launch_bounds__(256) void scat2_kernel(const unsigned* __restrict__ hlb,
                                                    const int* __restrict__ soffs,
                                                    const int2* __restrict__ csc,
                                                    unsigned* __restrict__ hmsg, int n) {
    const int lane = threadIdx.x & 63;
    const int wlocal = __builtin_amdgcn_readfirstlane(threadIdx.x >> 6);
    const int wstart = blockIdx.x * 4 + wlocal;
    const int wstride = gridDim.x * 4;

    for (int s = wstart; s < n; s += wstride) {
        unsigned rv = hlb[(size_t)s * 64 + lane];     // streaming: wave = one row
        float vx = bflo(rv), vy = bfhi(rv);
        const int e0 = soffs[s], e1 = soffs[s + 1];
        for (int e = e0; e < e1; e++) {
            int2 c = csc[e];                          // scalar (wave-uniform) load
            float nf = __int_as_float(c.y);
            unsigned lo = (unsigned)f32_to_bf16_rne(vx * nf);
            unsigned hi = (unsigned)f32_to_bf16_rne(vy * nf);
            unsigned val = lo | (hi << 16);
            unsigned* p = hmsg + (((size_t)c.x) << 6) + lane;
            asm volatile("global_atomic_pk_add_bf16 %0, %1, off"
                         :: "v"(p), "v"(val) : "memory");
        }
    }
}

// ---------------- Phase B: streaming finalize (self loop + bias + relu) ----------------

template <int POOL>
__global__ __launch_bounds__(256) void finb_kernel(const unsigned* __restrict__ hmsg,
                                                   const unsigned* __restrict__ hlb,
                                                   const float* __restrict__ dinv,
                                                   const float* __restrict__ bias,
                                                   void* __restrict__ outp,
                                                   const int* __restrict__ batch, int n) {
    const int lane = threadIdx.x & 63;
    const int wlocal = __builtin_amdgcn_readfirstlane(threadIdx.x >> 6);
    const int wstart = blockIdx.x * 4 + wlocal;
    const int wstride = gridDim.x * 4;
    const float2 bv = ((const float2*)bias)[lane];

    for (int i = wstart; i < n; i += wstride) {
        unsigned m = hmsg[(size_t)i * 64 + lane];
        unsigned s = hlb[(size_t)i * 64 + lane];
        float di = dinv[i];
        float w = di * di;
        float rx = fmaxf(bflo(m) + bflo(s) * w + bv.x, 0.0f);
        float ry = fmaxf(bfhi(m) + bfhi(s) * w + bv.y, 0.0f);
        if (POOL) {
            int g = batch[i];
            float* out = (float*)outp;
            atomicMax((int*)&out[(size_t)g * F + 2 * lane + 0], __float_as_int(rx));
            atomicMax((int*)&out[(size_t)g * F + 2 * lane + 1], __float_as_int(ry));
        } else {
            unsigned lo = (unsigned)f32_to_bf16_rne(rx);
            unsigned hi = (unsigned)f32_to_bf16_rne(ry);
            ((unsigned*)outp)[(size_t)i * 64 + lane] = lo | (hi << 16);
        }
    }
}

// ---------------- MLP head + log_softmax ----------------

__global__ __launch_bounds__(128) void mlp_kernel(const float* __restrict__ pooled,
                                                  const float* __restrict__ Wp1,
                                                  const float* __restrict__ bp1,
                                                  const float* __restrict__ Wp2,
                                                  const float* __restrict__ bp2,
                                                  float* __restrict__ out) {
    __shared__ float pl[F];
    __shared__ float s0[2], s1[2];
    int g = blockIdx.x, t = threadIdx.x;
    pl[t] = pooled[(size_t)g * F + t];
    __syncthreads();
    float a = bp1[t];
    #pragma unroll 8
    for (int k = 0; k < F; k++) a += pl[k] * Wp1[k * F + t];
    float p0 = a * Wp2[t * 2 + 0];
    float p1 = a * Wp2[t * 2 + 1];
    #pragma unroll
    for (int d = 32; d > 0; d >>= 1) {
        p0 += __shfl_down(p0, d, 64);
        p1 += __shfl_down(p1, d, 64);
    }
    if ((t & 63) == 0) { s0[t >> 6] = p0; s1[t >> 6] = p1; }
    __syncthreads();
    if (t == 0) {
        float l0 = s0[0] + s0[1] + bp2[0];
        float l1 = s1[0] + s1[1] + bp2[1];
        float m = fmaxf(l0, l1);
        float lse = m + logf(expf(l0 - m) + expf(l1 - m));
        out[g * 2 + 0] = l0 - lse;
        out[g * 2 + 1] = l1 - lse;
    }
}

// ---------------- launch ----------------

extern "C" void kernel_launch(void* const* d_in, const int* in_sizes, int n_in,
                              void* d_out, int out_size, void* d_ws, size_t ws_size,
                              hipStream_t stream) {
    const float* x    = (const float*)d_in[0];
    const int*   ei   = (const int*)d_in[1];
    const int*   batch= (const int*)d_in[2];
    const float* W1 = (const float*)d_in[3];  const float* b1 = (const float*)d_in[4];
    const float* W2 = (const float*)d_in[5];  const float* b2 = (const float*)d_in[6];
    const float* W3 = (const float*)d_in[7];  const float* b3 = (const float*)d_in[8];
    const float* Wp1= (const float*)d_in[9];  const float* bp1= (const float*)d_in[10];
    const float* Wp2= (const float*)d_in[11]; const float* bp2= (const float*)d_in[12];

    const int N = in_sizes[0] / F;
    const int E = in_sizes[1] / 2;
    const int G = out_size / 2;

    char* w = (char*)d_ws;
    size_t off = 0;
    auto alloc = [&](size_t bytes) -> void* {
        void* p = w + off;
        off = (off + bytes + 255) & ~(size_t)255;
        return p;
    };
    unsigned short* xb   = (unsigned short*)alloc((size_t)N * F * 2);
    unsigned short* hlb  = (unsigned short*)alloc((size_t)N * F * 2);  // GEMM out (bf16)
    unsigned short* hab  = (unsigned short*)alloc((size_t)N * F * 2);  // layer out (bf16)
    unsigned*       hmsg = (unsigned*)alloc((size_t)N * F * 2);        // bf16 accum
    unsigned short* Wt1  = (unsigned short*)alloc((size_t)F * F * 2);
    unsigned short* Wt2  = (unsigned short*)alloc((size_t)F * F * 2);
    unsigned short* Wt3  = (unsigned short*)alloc((size_t)F * F * 2);
    int*   cntd   = (int*)alloc((size_t)N * 4);
    int*   cnts   = (int*)alloc((size_t)N * 4);
    int*   curs   = (int*)alloc((size_t)N * 4);
    int*   soffs  = (int*)alloc((size_t)(N + 1) * 4);
    float* dinv   = (float*)alloc((size_t)N * 4);
    int2*  csc    = (int2*)alloc((size_t)E * 8);
    float* pooled = (float*)alloc((size_t)G * F * 4);

    const int* srcp = ei;
    const int* dstp = ei + E;

    hipMemsetAsync(cntd, 0, (size_t)N * 4, stream);
    hipMemsetAsync(cnts, 0, (size_t)N * 4, stream);
    hipMemsetAsync(curs, 0, (size_t)N * 4, stream);
    hipMemsetAsync(pooled, 0, (size_t)G * F * 4, stream);

    const int eb = (E + 255) / 256;
    const int nb = (N + 255) / 256;
    cvtx_kernel<<<2048, 256, 0, stream>>>((const float4*)x, (ushort4*)xb, (long)N * F / 4);
    cvtw_kernel<<<F, F, 0, stream>>>(W1, Wt1);
    cvtw_kernel<<<F, F, 0, stream>>>(W2, Wt2);
    cvtw_kernel<<<F, F, 0, stream>>>(W3, Wt3);
    count2_kernel<<<eb, 256, 0, stream>>>(srcp, dstp, cntd, cnts, E);
    dinv_kernel<<<nb, 256, 0, stream>>>(cntd, dinv, N);
    scan_kernel<<<1, 1024, 0, stream>>>(cnts, soffs, N);
    fillc_kernel<<<eb, 256, 0, stream>>>(srcp, dstp, soffs, curs, dinv, csc, E);

    const int gb = (N + 63) / 64;
    const int pb = 2048;
    const size_t msgbytes = (size_t)N * F * 2;

    // L1
    gemm_mfma<<<gb, 256, 0, stream>>>(xb, Wt1, hlb, N);
    hipMemsetAsync(hmsg, 0, msgbytes, stream);
    scat2_kernel<<<pb, 256, 0, stream>>>((const unsigned*)hlb, soffs, csc, hmsg, N);
    finb_kernel<0><<<pb, 256, 0, stream>>>(hmsg, (const unsigned*)hlb, dinv, b1, hab, nullptr, N);
    // L2
    gemm_mfma<<<gb, 256, 0, stream>>>(hab, Wt2, hlb, N);
    hipMemsetAsync(hmsg, 0, msgbytes, stream);
    scat2_kernel<<<pb, 256, 0, stream>>>((const unsigned*)hlb, soffs, csc, hmsg, N);
    finb_kernel<0><<<pb, 256, 0, stream>>>(hmsg, (const unsigned*)hlb, dinv, b2, hab, nullptr, N);
    // L3 + pool
    gemm_mfma<<<gb, 256, 0, stream>>>(hab, Wt3, hlb, N);
    hipMemsetAsync(hmsg, 0, msgbytes, stream);
    scat2_kernel<<<pb, 256, 0, stream>>>((const unsigned*)hlb, soffs, csc, hmsg, N);
    finb_kernel<1><<<pb, 256, 0, stream>>>(hmsg, (const unsigned*)hlb, dinv, b3, pooled, batch, N);

    mlp_kernel<<<G, 128, 0, stream>>>(pooled, Wp1, bp1, Wp2, bp2, (float*)d_out);
}

// Round 12
// 763.265 us; speedup vs baseline: 2.1674x; 2.1674x over previous
//
#include <hip/hip_runtime.h>

#define F 128
#define NPART 16   // src partitions (6250 nodes * 256B = 1.6MB, L2-resident)
#define NXCD 8

typedef __attribute__((ext_vector_type(8))) short bf16x8;
typedef __attribute__((ext_vector_type(4))) float f32x4;

// ---------------- bf16 helpers ----------------

__device__ __forceinline__ unsigned short f32_to_bf16_rne(float x) {
    unsigned u = __float_as_uint(x);
    unsigned r = (u + 0x7fffu + ((u >> 16) & 1u)) >> 16;   // round to nearest even
    return (unsigned short)r;
}

__device__ __forceinline__ float bfhi(unsigned v) { return __uint_as_float(v & 0xffff0000u); }
__device__ __forceinline__ float bflo(unsigned v) { return __uint_as_float(v << 16); }

// ---------------- converts ----------------

__global__ __launch_bounds__(256) void cvtx_kernel(const float4* __restrict__ x4,
                                                   ushort4* __restrict__ xb4, long n4) {
    long stride = (long)gridDim.x * 256;
    for (long i = blockIdx.x * 256 + threadIdx.x; i < n4; i += stride) {
        float4 v = x4[i];
        ushort4 o;
        o.x = f32_to_bf16_rne(v.x);
        o.y = f32_to_bf16_rne(v.y);
        o.z = f32_to_bf16_rne(v.z);
        o.w = f32_to_bf16_rne(v.w);
        xb4[i] = o;
    }
}

__global__ __launch_bounds__(128) void cvtw_kernel(const float* __restrict__ W,
                                                   unsigned short* __restrict__ Wt) {
    int c = blockIdx.x, k = threadIdx.x;
    Wt[c * F + k] = f32_to_bf16_rne(W[k * F + c]);
}

// ---------------- MFMA GEMM ----------------

__global__ __launch_bounds__(256) void gemm_mfma(const unsigned short* __restrict__ hb,
                                                 const unsigned short* __restrict__ Wt,
                                                 unsigned short* __restrict__ outb, int n) {
    __shared__ unsigned short sm[4][16][F + 4];   // +4 pad: conflict-free repack
    const int tid = threadIdx.x;
    const int w = tid >> 6, lane = tid & 63;
    const int r = lane & 15, kg = lane >> 4;
    const long base = (long)blockIdx.x * 64 + w * 16;

    int arow = (int)(base + r);
    if (arow >= n) arow = n - 1;
    const bf16x8* __restrict__ arowp = (const bf16x8*)(hb + (size_t)arow * F);

    f32x4 acc[8] = {};
    #pragma unroll
    for (int c = 0; c < 4; c++) {
        bf16x8 a = arowp[c * 4 + kg];
        #pragma unroll
        for (int t = 0; t < 8; t++) {
            bf16x8 b = *(const bf16x8*)(Wt + (size_t)(t * 16 + r) * F + c * 32 + kg * 8);
            acc[t] = __builtin_amdgcn_mfma_f32_16x16x32_bf16(a, b, acc[t], 0, 0, 0);
        }
    }

    #pragma unroll
    for (int t = 0; t < 8; t++)
        #pragma unroll
        for (int j = 0; j < 4; j++)
            sm[w][kg * 4 + j][t * 16 + r] = f32_to_bf16_rne(acc[t][j]);
    #pragma unroll
    for (int it = 0; it < 4; it++) {
        int row = it * 4 + kg;
        long grow = base + row;
        if (grow < n) {
            uint4 v = *(uint4*)&sm[w][row][r * 8];
            *(uint4*)(outb + (size_t)grow * F + r * 8) = v;
        }
    }
}

// ---------------- primary build: (partition, dst) binned edges ----------------

__global__ __launch_bounds__(256) void count16_kernel(const int* __restrict__ src,
                                                      const int* __restrict__ dst,
                                                      int* __restrict__ cnt16,
                                                      int* __restrict__ cntd,
                                                      int chunk, int n, int e) {
    int i = blockIdx.x * 256 + threadIdx.x;
    if (i >= e) return;
    int s = src[i], d = dst[i];
    unsigned p = (unsigned)s / (unsigned)chunk;
    atomicAdd(&cnt16[(size_t)p * n + d], 1);
    atomicAdd(&cntd[d], 1);
}

__global__ __launch_bounds__(256) void dinv_kernel(const int* __restrict__ cnt,
                                                   float* __restrict__ dinv, int n) {
    int i = blockIdx.x * 256 + threadIdx.x;
    if (i < n) dinv[i] = rsqrtf((float)(cnt[i] + 1));
}

// 3-phase coalesced scan over M elements
__global__ __launch_bounds__(256) void scanA_kernel(const int* __restrict__ cnt,
                                                    int* __restrict__ bsum, int M) {
    __shared__ int sm[256];
    int t = threadIdx.x;
    int i = blockIdx.x * 256 + t;
    int v = (i < M) ? cnt[i] : 0;
    sm[t] = v;
    __syncthreads();
    for (int d = 128; d > 0; d >>= 1) {
        if (t < d) sm[t] += sm[t + d];
        __syncthreads();
    }
    if (t == 0) bsum[blockIdx.x] = sm[0];
}

__global__ __launch_bounds__(1024) void scanB_kernel(const int* __restrict__ bsum,
                                                     int* __restrict__ bpre,
                                                     int* __restrict__ offs, int nb, int M) {
    __shared__ int sm[1024];
    int t = threadIdx.x;
    int chunk = (nb + 1023) >> 10;
    int b = t * chunk;
    int e = b + chunk; if (e > nb) e = nb;
    int s = 0;
    for (int i = b; i < e; i++) s += bsum[i];
    sm[t] = s;
    __syncthreads();
    for (int d = 1; d < 1024; d <<= 1) {
        int v = 0;
        if (t >= d) v = sm[t - d];
        __syncthreads();
        if (t >= d) sm[t] += v;
        __syncthreads();
    }
    int run = (t == 0) ? 0 : sm[t - 1];
    for (int i = b; i < e; i++) { bpre[i] = run; run += bsum[i]; }
    if (t == 1023) offs[M] = sm[1023];
}

__global__ __launch_bounds__(256) void scanC_kernel(const int* __restrict__ cnt,
                                                    const int* __restrict__ bpre,
                                                    int* __restrict__ offs, int M) {
    __shared__ int sm[256];
    int t = threadIdx.x;
    int i = blockIdx.x * 256 + t;
    int v = (i < M) ? cnt[i] : 0;
    sm[t] = v;
    __syncthreads();
    // inclusive scan
    for (int d = 1; d < 256; d <<= 1) {
        int u = 0;
        if (t >= d) u = sm[t - d];
        __syncthreads();
        if (t >= d) sm[t] += u;
        __syncthreads();
    }
    if (i < M) offs[i] = bpre[blockIdx.x] + sm[t] - v;   // exclusive
}

__global__ __launch_bounds__(256) void fill16_kernel(const int* __restrict__ src,
                                                     const int* __restrict__ dst,
                                                     const int* __restrict__ offs16,
                                                     int* __restrict__ cur16,
                                                     const float* __restrict__ dinv,
                                                     int2* __restrict__ csr16,
                                                     int chunk, int n, int e) {
    int i = blockIdx.x * 256 + threadIdx.x;
    if (i >= e) return;
    int s = src[i], d = dst[i];
    unsigned p = (unsigned)s / (unsigned)chunk;
    size_t bin = (size_t)p * n + d;
    int pos = offs16[bin] + atomicAdd(&cur16[bin], 1);
    csr16[pos] = make_int2(s, __float_as_int(dinv[s] * dinv[d]));
}

// ---------------- Phase A: XCD-partitioned gather -> bf16 partials ----------------
// Block with (blockIdx&7)==x processes partitions x and x+8 only: per-XCD gather
// working set = 3.2MB (L2-resident if blockIdx%8 == XCD). part[x][d] = partial row.

__global__ __launch_bounds__(256) void aggP_kernel(const unsigned* __restrict__ hlb,
                                                   const int* __restrict__ offs16,
                                                   const int2* __restrict__ csr16,
                                                   unsigned* __restrict__ part, int n) {
    const int lane = threadIdx.x & 63;
    const int wlocal = __builtin_amdgcn_readfirstlane(threadIdx.x >> 6);
    const int x = blockIdx.x & 7;
    const int pgw = ((blockIdx.x >> 3) << 2) + wlocal;       // wave id within xcd-group
    const int stride = (gridDim.x >> 3) << 2;                // waves per xcd-group

    for (int d = pgw; d < n; d += stride) {
        float ax = 0.0f, ay = 0.0f;
        #pragma unroll
        for (int pp = 0; pp < 2; pp++) {
            size_t bin = (size_t)(x + pp * 8) * n + d;
            int e0 = offs16[bin], e1 = offs16[bin + 1];
            for (int e = e0; e < e1; e++) {
                int2 c = csr16[e];
                unsigned r = hlb[((size_t)c.x << 6) + lane];
                float nf = __int_as_float(c.y);
                ax += bflo(r) * nf;
                ay += bfhi(r) * nf;
            }
        }
        unsigned lo = (unsigned)f32_to_bf16_rne(ax);
        unsigned hi = (unsigned)f32_to_bf16_rne(ay);
        part[((size_t)x * n + d) * 64 + lane] = lo | (hi << 16);
    }
}

// ---------------- Phase B: reduce 8 partials + self loop + bias + relu ----------------

template <int POOL>
__global__ __launch_bounds__(256) void reduceK_kernel(const unsigned* __restrict__ part,
                                                      const unsigned* __restrict__ hlb,
                                                      const float* __restrict__ dinv,
                                                      const float* __restrict__ bias,
                                                      void* __restrict__ outp,
                                                      const int* __restrict__ batch, int n) {
    const int lane = threadIdx.x & 63;
    const int wlocal = __builtin_amdgcn_readfirstlane(threadIdx.x >> 6);
    const int wstart = blockIdx.x * 4 + wlocal;
    const int wstride = gridDim.x * 4;
    const float2 bv = ((const float2*)bias)[lane];

    for (int i = wstart; i < n; i += wstride) {
        float ax = 0.0f, ay = 0.0f;
        #pragma unroll
        for (int p = 0; p < 8; p++) {
            unsigned v = part[((size_t)p * n + i) * 64 + lane];
            ax += bflo(v);
            ay += bfhi(v);
        }
        {
            float di = dinv[i];
            float w = di * di;
            unsigned s = hlb[((size_t)i << 6) + lane];
            ax += bflo(s) * w;
            ay += bfhi(s) * w;
        }
        float rx = fmaxf(ax + bv.x, 0.0f);
        float ry = fmaxf(ay + bv.y, 0.0f);
        if (POOL) {
            int g = batch[i];
            float* out = (float*)outp;
            atomicMax((int*)&out[(size_t)g * F + 2 * lane + 0], __float_as_int(rx));
            atomicMax((int*)&out[(size_t)g * F + 2 * lane + 1], __float_as_int(ry));
        } else {
            unsigned lo = (unsigned)f32_to_bf16_rne(rx);
            unsigned hi = (unsigned)f32_to_bf16_rne(ry);
            ((unsigned*)outp)[((size_t)i << 6) + lane] = lo | (hi << 16);
        }
    }
}

// ---------------- FALLBACK (R10): single-CSR build + gather agg ----------------

__global__ __launch_bounds__(256) void count_kernel(const int* __restrict__ dst,
                                                    int* __restrict__ cnt, int e) {
    int i = blockIdx.x * 256 + threadIdx.x;
    if (i < e) atomicAdd(&cnt[dst[i]], 1);
}

__global__ __launch_bounds__(1024) void scan_kernel(const int* __restrict__ cnt,
                                                    int* __restrict__ offs, int n) {
    __shared__ int sm[1024];
    int tid = threadIdx.x;
    int chunk = (n + 1023) >> 10;
    int b = tid * chunk;
    int e = b + chunk; if (e > n) e = n;
    int s = 0;
    for (int i = b; i < e; i++) s += cnt[i];
    sm[tid] = s;
    __syncthreads();
    for (int d = 1; d < 1024; d <<= 1) {
        int v = 0;
        if (tid >= d) v = sm[tid - d];
        __syncthreads();
        if (tid >= d) sm[tid] += v;
        __syncthreads();
    }
    int run = (tid == 0) ? 0 : sm[tid - 1];
    for (int i = b; i < e; i++) { offs[i] = run; run += cnt[i]; }
    if (tid == 1023) offs[n] = sm[1023];
}

__global__ __launch_bounds__(256) void fill_kernel(const int* __restrict__ src,
                                                   const int* __restrict__ dst,
                                                   const int* __restrict__ offs,
                                                   int* __restrict__ cursor,
                                                   const float* __restrict__ dinv,
                                                   int2* __restrict__ csr, int e) {
    int i = blockIdx.x * 256 + threadIdx.x;
    if (i >= e) return;
    int s = src[i], d = dst[i];
    int pos = atomicAdd(&cursor[d], 1);
    csr[offs[d] + pos] = make_int2(s, __float_as_int(dinv[s] * dinv[d]));
}

template <int POOL>
__global__ __launch_bounds__(256) void agg_kernel(const unsigned* __restrict__ hlb,
                                                  const int* __restrict__ offs,
                                                  const int2* __restrict__ csr,
                                                  const float* __restrict__ dinv,
                                                  const float* __restrict__ bias,
                                                  void* __restrict__ outp,
                                                  const int* __restrict__ batch, int n) {
    const int lane = threadIdx.x & 63;
    const int wlocal = __builtin_amdgcn_readfirstlane(threadIdx.x >> 6);
    const int wstart = blockIdx.x * 4 + wlocal;
    const int wstride = gridDim.x * 4;
    const unsigned* __restrict__ rowp = hlb + lane;
    const float2 bv = ((const float2*)bias)[lane];

    for (int i = wstart; i < n; i += wstride) {
        float ax = 0.0f, ay = 0.0f;
        const int e0 = offs[i], e1 = offs[i + 1];
        int nb = (e1 - e0) >> 3;
        int2 cc0, cc1, cc2, cc3, cc4, cc5, cc6, cc7;
        int e = e0;
        if (nb > 0) {
            cc0 = csr[e + 0]; cc1 = csr[e + 1]; cc2 = csr[e + 2]; cc3 = csr[e + 3];
            cc4 = csr[e + 4]; cc5 = csr[e + 5]; cc6 = csr[e + 6]; cc7 = csr[e + 7];
        }
        for (int b = 0; b < nb; b++) {
            unsigned r0 = rowp[(size_t)cc0.x << 6];
            unsigned r1 = rowp[(size_t)cc1.x << 6];
            unsigned r2 = rowp[(size_t)cc2.x << 6];
            unsigned r3 = rowp[(size_t)cc3.x << 6];
            unsigned r4 = rowp[(size_t)cc4.x << 6];
            unsigned r5 = rowp[(size_t)cc5.x << 6];
            unsigned r6 = rowp[(size_t)cc6.x << 6];
            unsigned r7 = rowp[(size_t)cc7.x << 6];
            float n0 = __int_as_float(cc0.y), n1 = __int_as_float(cc1.y);
            float n2 = __int_as_float(cc2.y), n3 = __int_as_float(cc3.y);
            float n4 = __int_as_float(cc4.y), n5 = __int_as_float(cc5.y);
            float n6 = __int_as_float(cc6.y), n7 = __int_as_float(cc7.y);
            e += 8;
            if (b + 1 < nb) {
                cc0 = csr[e + 0]; cc1 = csr[e + 1]; cc2 = csr[e + 2]; cc3 = csr[e + 3];
                cc4 = csr[e + 4]; cc5 = csr[e + 5]; cc6 = csr[e + 6]; cc7 = csr[e + 7];
            }
            ax += bflo(r0) * n0 + bflo(r1) * n1 + bflo(r2) * n2 + bflo(r3) * n3
                + bflo(r4) * n4 + bflo(r5) * n5 + bflo(r6) * n6 + bflo(r7) * n7;
            ay += bfhi(r0) * n0 + bfhi(r1) * n1 + bfhi(r2) * n2 + bfhi(r3) * n3
                + bfhi(r4) * n4 + bfhi(r5) * n5 + bfhi(r6) * n6 + bfhi(r7) * n7;
        }
        for (; e < e1; e++) {
            int2 c = csr[e];
            unsigned r = rowp[(size_t)c.x << 6];
            float nf = __int_as_float(c.y);
            ax += bflo(r) * nf;
            ay += bfhi(r) * nf;
        }
        {
            float di = dinv[i];
            unsigned r = rowp[(size_t)i << 6];
            ax += bflo(r) * di * di;
            ay += bfhi(r) * di * di;
        }
        float rx = fmaxf(ax + bv.x, 0.0f);
        float ry = fmaxf(ay + bv.y, 0.0f);
        if (POOL) {
            int g = batch[i];
            float* out = (float*)outp;
            atomicMax((int*)&out[(size_t)g * F + 2 * lane + 0], __float_as_int(rx));
            atomicMax((int*)&out[(size_t)g * F + 2 * lane + 1], __float_as_int(ry));
        } else {
            unsigned lo = f32_to_bf16_rne(rx);
            unsigned hi = f32_to_bf16_rne(ry);
            ((unsigned*)outp)[(size_t)i * 64 + lane] = lo | (hi << 16);
        }
    }
}

// ---------------- MLP head + log_softmax ----------------

__global__ __launch_bounds__(128) void mlp_kernel(const float* __restrict__ pooled,
                                                  const float* __restrict__ Wp1,
                                                  const float* __restrict__ bp1,
                                                  const float* __restrict__ Wp2,
                                                  const float* __restrict__ bp2,
                                                  float* __restrict__ out) {
    __shared__ float pl[F];
    __shared__ float s0[2], s1[2];
    int g = blockIdx.x, t = threadIdx.x;
    pl[t] = pooled[(size_t)g * F + t];
    __syncthreads();
    float a = bp1[t];
    #pragma unroll 8
    for (int k = 0; k < F; k++) a += pl[k] * Wp1[k * F + t];
    float p0 = a * Wp2[t * 2 + 0];
    float p1 = a * Wp2[t * 2 + 1];
    #pragma unroll
    for (int d = 32; d > 0; d >>= 1) {
        p0 += __shfl_down(p0, d, 64);
        p1 += __shfl_down(p1, d, 64);
    }
    if ((t & 63) == 0) { s0[t >> 6] = p0; s1[t >> 6] = p1; }
    __syncthreads();
    if (t == 0) {
        float l0 = s0[0] + s0[1] + bp2[0];
        float l1 = s1[0] + s1[1] + bp2[1];
        float m = fmaxf(l0, l1);
        float lse = m + logf(expf(l0 - m) + expf(l1 - m));
        out[g * 2 + 0] = l0 - lse;
        out[g * 2 + 1] = l1 - lse;
    }
}

// ---------------- launch ----------------

extern "C" void kernel_launch(void* const* d_in, const int* in_sizes, int n_in,
                              void* d_out, int out_size, void* d_ws, size_t ws_size,
                              hipStream_t stream) {
    const float* x    = (const float*)d_in[0];
    const int*   ei   = (const int*)d_in[1];
    const int*   batch= (const int*)d_in[2];
    const float* W1 = (const float*)d_in[3];  const float* b1 = (const float*)d_in[4];
    const float* W2 = (const float*)d_in[5];  const float* b2 = (const float*)d_in[6];
    const float* W3 = (const float*)d_in[7];  const float* b3 = (const float*)d_in[8];
    const float* Wp1= (const float*)d_in[9];  const float* bp1= (const float*)d_in[10];
    const float* Wp2= (const float*)d_in[11]; const float* bp2= (const float*)d_in[12];

    const int N = in_sizes[0] / F;
    const int E = in_sizes[1] / 2;
    const int G = out_size / 2;
    const int* srcp = ei;
    const int* dstp = ei + E;
    const int eb = (E + 255) / 256;
    const int nb = (N + 255) / 256;

    char* w = (char*)d_ws;
    size_t off = 0;
    auto alloc = [&](size_t bytes) -> void* {
        void* p = w + off;
        off = (off + bytes + 255) & ~(size_t)255;
        return p;
    };

    // ---- primary layout ----
    unsigned short* xb   = (unsigned short*)alloc((size_t)N * F * 2);
    unsigned short* hlb  = (unsigned short*)alloc((size_t)N * F * 2);
    unsigned short* hab  = (unsigned short*)alloc((size_t)N * F * 2);
    unsigned*       part = (unsigned*)alloc((size_t)NXCD * N * F * 2);
    unsigned short* Wt1  = (unsigned short*)alloc((size_t)F * F * 2);
    unsigned short* Wt2  = (unsigned short*)alloc((size_t)F * F * 2);
    unsigned short* Wt3  = (unsigned short*)alloc((size_t)F * F * 2);
    const size_t M = (size_t)NPART * N;
    int*   cnt16  = (int*)alloc(M * 4);
    int*   cur16  = (int*)alloc(M * 4);
    int*   offs16 = (int*)alloc((M + 1) * 4);
    int*   bsum   = (int*)alloc(((M + 255) / 256) * 4);
    int*   bpre   = (int*)alloc(((M + 255) / 256) * 4);
    int*   cntd   = (int*)alloc((size_t)N * 4);
    float* dinv   = (float*)alloc((size_t)N * 4);
    int2*  csr16  = (int2*)alloc((size_t)E * 8);
    float* pooled = (float*)alloc((size_t)G * F * 4);
    size_t need_primary = off;

    if (need_primary <= ws_size) {
        const int chunk = (N + NPART - 1) / NPART;
        const int nblkM = (int)((M + 255) / 256);

        hipMemsetAsync(cnt16, 0, M * 4, stream);
        hipMemsetAsync(cur16, 0, M * 4, stream);
        hipMemsetAsync(cntd,  0, (size_t)N * 4, stream);
        hipMemsetAsync(pooled, 0, (size_t)G * F * 4, stream);

        cvtx_kernel<<<2048, 256, 0, stream>>>((const float4*)x, (ushort4*)xb, (long)N * F / 4);
        cvtw_kernel<<<F, F, 0, stream>>>(W1, Wt1);
        cvtw_kernel<<<F, F, 0, stream>>>(W2, Wt2);
        cvtw_kernel<<<F, F, 0, stream>>>(W3, Wt3);

        count16_kernel<<<eb, 256, 0, stream>>>(srcp, dstp, cnt16, cntd, chunk, N, E);
        dinv_kernel<<<nb, 256, 0, stream>>>(cntd, dinv, N);
        scanA_kernel<<<nblkM, 256, 0, stream>>>(cnt16, bsum, (int)M);
        scanB_kernel<<<1, 1024, 0, stream>>>(bsum, bpre, offs16, nblkM, (int)M);
        scanC_kernel<<<nblkM, 256, 0, stream>>>(cnt16, bpre, offs16, (int)M);
        fill16_kernel<<<eb, 256, 0, stream>>>(srcp, dstp, offs16, cur16, dinv, csr16, chunk, N, E);

        const int gb = (N + 63) / 64;
        const int pb = 2048;   // multiple of 8; persistent

        gemm_mfma<<<gb, 256, 0, stream>>>(xb, Wt1, hlb, N);
        aggP_kernel<<<pb, 256, 0, stream>>>((const unsigned*)hlb, offs16, csr16, part, N);
        reduceK_kernel<0><<<pb, 256, 0, stream>>>(part, (const unsigned*)hlb, dinv, b1, hab, nullptr, N);

        gemm_mfma<<<gb, 256, 0, stream>>>(hab, Wt2, hlb, N);
        aggP_kernel<<<pb, 256, 0, stream>>>((const unsigned*)hlb, offs16, csr16, part, N);
        reduceK_kernel<0><<<pb, 256, 0, stream>>>(part, (const unsigned*)hlb, dinv, b2, hab, nullptr, N);

        gemm_mfma<<<gb, 256, 0, stream>>>(hab, Wt3, hlb, N);
        aggP_kernel<<<pb, 256, 0, stream>>>((const unsigned*)hlb, offs16, csr16, part, N);
        reduceK_kernel<1><<<pb, 256, 0, stream>>>(part, (const unsigned*)hlb, dinv, b3, pooled, batch, N);

        mlp_kernel<<<G, 128, 0, stream>>>(pooled, Wp1, bp1, Wp2, bp2, (float*)d_out);
        return;
    }

    // ---- fallback: R10 path ----
    off = 0;
    unsigned short* fxb  = (unsigned short*)alloc((size_t)N * F * 2);
    unsigned short* fhlb = (unsigned short*)alloc((size_t)N * F * 2);
    unsigned short* fhab = (unsigned short*)alloc((size_t)N * F * 2);
    unsigned short* fWt1 = (unsigned short*)alloc((size_t)F * F * 2);
    unsigned short* fWt2 = (unsigned short*)alloc((size_t)F * F * 2);
    unsigned short* fWt3 = (unsigned short*)alloc((size_t)F * F * 2);
    int*   deg    = (int*)alloc((size_t)N * 4);
    int*   cursor = (int*)alloc((size_t)N * 4);
    int*   offs   = (int*)alloc((size_t)(N + 1) * 4);
    float* fdinv  = (float*)alloc((size_t)N * 4);
    int2*  csr    = (int2*)alloc((size_t)E * 8);
    float* fpool  = (float*)alloc((size_t)G * F * 4);

    hipMemsetAsync(deg,    0, (size_t)N * 4, stream);
    hipMemsetAsync(cursor, 0, (size_t)N * 4, stream);
    hipMemsetAsync(fpool,  0, (size_t)G * F * 4, stream);

    cvtx_kernel<<<2048, 256, 0, stream>>>((const float4*)x, (ushort4*)fxb, (long)N * F / 4);
    cvtw_kernel<<<F, F, 0, stream>>>(W1, fWt1);
    cvtw_kernel<<<F, F, 0, stream>>>(W2, fWt2);
    cvtw_kernel<<<F, F, 0, stream>>>(W3, fWt3);
    count_kernel<<<eb, 256, 0, stream>>>(dstp, deg, E);
    dinv_kernel<<<nb, 256, 0, stream>>>(deg, fdinv, N);
    scan_kernel<<<1, 1024, 0, stream>>>(deg, offs, N);
    fill_kernel<<<eb, 256, 0, stream>>>(srcp, dstp, offs, cursor, fdinv, csr, E);

    const int gb = (N + 63) / 64;
    const int ab = 2048;
    gemm_mfma<<<gb, 256, 0, stream>>>(fxb, fWt1, fhlb, N);
    agg_kernel<0><<<ab, 256, 0, stream>>>((const unsigned*)fhlb, offs, csr, fdinv, b1, fhab, nullptr, N);
    gemm_mfma<<<gb, 256, 0, stream>>>(fhab, fWt2, fhlb, N);
    agg_kernel<0><<<ab, 256, 0, stream>>>((const unsigned*)fhlb, offs, csr, fdinv, b2, fhab, nullptr, N);
    gemm_mfma<<<gb, 256, 0, stream>>>(fhab, fWt3, fhlb, N);
    agg_kernel<1><<<ab, 256, 0, stream>>>((const unsigned*)fhlb, offs, csr, fdinv, b3, fpool, batch, N);
    mlp_kernel<<<G, 128, 0, stream>>>(fpool, Wp1, bp1, Wp2, bp2, (float*)d_out);
}

// Round 13
// 681.760 us; speedup vs baseline: 2.4265x; 1.1196x over previous
//
#include <hip/hip_runtime.h>

#define F 128
#define PSH 13            // src partition = s >> 13 (8192 nodes = 2MB bf16), p in [0,13)
#define NP 13

typedef __attribute__((ext_vector_type(8))) short bf16x8;
typedef __attribute__((ext_vector_type(4))) float f32x4;

// ---------------- bf16 helpers ----------------

__device__ __forceinline__ unsigned short f32_to_bf16_rne(float x) {
    unsigned u = __float_as_uint(x);
    unsigned r = (u + 0x7fffu + ((u >> 16) & 1u)) >> 16;   // round to nearest even
    return (unsigned short)r;
}

__device__ __forceinline__ float bfhi(unsigned v) { return __uint_as_float(v & 0xffff0000u); }
__device__ __forceinline__ float bflo(unsigned v) { return __uint_as_float(v << 16); }

// ---------------- converts ----------------

__global__ __launch_bounds__(256) void cvtx_kernel(const float4* __restrict__ x4,
                                                   ushort4* __restrict__ xb4, long n4) {
    long stride = (long)gridDim.x * 256;
    for (long i = blockIdx.x * 256 + threadIdx.x; i < n4; i += stride) {
        float4 v = x4[i];
        ushort4 o;
        o.x = f32_to_bf16_rne(v.x);
        o.y = f32_to_bf16_rne(v.y);
        o.z = f32_to_bf16_rne(v.z);
        o.w = f32_to_bf16_rne(v.w);
        xb4[i] = o;
    }
}

__global__ __launch_bounds__(128) void cvtw_kernel(const float* __restrict__ W,
                                                   unsigned short* __restrict__ Wt) {
    int c = blockIdx.x, k = threadIdx.x;
    Wt[c * F + k] = f32_to_bf16_rne(W[k * F + c]);
}

// ---------------- MFMA GEMM ----------------

__global__ __launch_bounds__(256) void gemm_mfma(const unsigned short* __restrict__ hb,
                                                 const unsigned short* __restrict__ Wt,
                                                 unsigned short* __restrict__ outb, int n) {
    __shared__ unsigned short sm[4][16][F + 4];
    const int tid = threadIdx.x;
    const int w = tid >> 6, lane = tid & 63;
    const int r = lane & 15, kg = lane >> 4;
    const long base = (long)blockIdx.x * 64 + w * 16;

    int arow = (int)(base + r);
    if (arow >= n) arow = n - 1;
    const bf16x8* __restrict__ arowp = (const bf16x8*)(hb + (size_t)arow * F);

    f32x4 acc[8] = {};
    #pragma unroll
    for (int c = 0; c < 4; c++) {
        bf16x8 a = arowp[c * 4 + kg];
        #pragma unroll
        for (int t = 0; t < 8; t++) {
            bf16x8 b = *(const bf16x8*)(Wt + (size_t)(t * 16 + r) * F + c * 32 + kg * 8);
            acc[t] = __builtin_amdgcn_mfma_f32_16x16x32_bf16(a, b, acc[t], 0, 0, 0);
        }
    }

    #pragma unroll
    for (int t = 0; t < 8; t++)
        #pragma unroll
        for (int j = 0; j < 4; j++)
            sm[w][kg * 4 + j][t * 16 + r] = f32_to_bf16_rne(acc[t][j]);
    #pragma unroll
    for (int it = 0; it < 4; it++) {
        int row = it * 4 + kg;
        long grow = base + row;
        if (grow < n) {
            uint4 v = *(uint4*)&sm[w][row][r * 8];
            *(uint4*)(outb + (size_t)grow * F + r * 8) = v;
        }
    }
}

// ---------------- build: edges binned by (wave-group gw = d>>4, src partition) ----------

__global__ __launch_bounds__(256) void count16_kernel(const int* __restrict__ src,
                                                      const int* __restrict__ dst,
                                                      int* __restrict__ cnt,
                                                      int* __restrict__ cntd, int e) {
    int i = blockIdx.x * 256 + threadIdx.x;
    if (i >= e) return;
    int s = src[i], d = dst[i];
    unsigned p = (unsigned)s >> PSH;
    atomicAdd(&cnt[(size_t)(d >> 4) * NP + p], 1);
    atomicAdd(&cntd[d], 1);
}

__global__ __launch_bounds__(256) void dinv_kernel(const int* __restrict__ cnt,
                                                   float* __restrict__ dinv, int n) {
    int i = blockIdx.x * 256 + threadIdx.x;
    if (i < n) dinv[i] = rsqrtf((float)(cnt[i] + 1));
}

// 3-phase coalesced scan over M elements
__global__ __launch_bounds__(256) void scanA_kernel(const int* __restrict__ cnt,
                                                    int* __restrict__ bsum, int M) {
    __shared__ int sm[256];
    int t = threadIdx.x;
    int i = blockIdx.x * 256 + t;
    int v = (i < M) ? cnt[i] : 0;
    sm[t] = v;
    __syncthreads();
    for (int d = 128; d > 0; d >>= 1) {
        if (t < d) sm[t] += sm[t + d];
        __syncthreads();
    }
    if (t == 0) bsum[blockIdx.x] = sm[0];
}

__global__ __launch_bounds__(1024) void scanB_kernel(const int* __restrict__ bsum,
                                                     int* __restrict__ bpre,
                                                     int* __restrict__ offs, int nb, int M) {
    __shared__ int sm[1024];
    int t = threadIdx.x;
    int chunk = (nb + 1023) >> 10;
    int b = t * chunk;
    int e = b + chunk; if (e > nb) e = nb;
    int s = 0;
    for (int i = b; i < e; i++) s += bsum[i];
    sm[t] = s;
    __syncthreads();
    for (int d = 1; d < 1024; d <<= 1) {
        int v = 0;
        if (t >= d) v = sm[t - d];
        __syncthreads();
        if (t >= d) sm[t] += v;
        __syncthreads();
    }
    int run = (t == 0) ? 0 : sm[t - 1];
    for (int i = b; i < e; i++) { bpre[i] = run; run += bsum[i]; }
    if (t == 1023) offs[M] = sm[1023];
}

__global__ __launch_bounds__(256) void scanC_kernel(const int* __restrict__ cnt,
                                                    const int* __restrict__ bpre,
                                                    int* __restrict__ offs, int M) {
    __shared__ int sm[256];
    int t = threadIdx.x;
    int i = blockIdx.x * 256 + t;
    int v = (i < M) ? cnt[i] : 0;
    sm[t] = v;
    __syncthreads();
    for (int d = 1; d < 256; d <<= 1) {
        int u = 0;
        if (t >= d) u = sm[t - d];
        __syncthreads();
        if (t >= d) sm[t] += u;
        __syncthreads();
    }
    if (i < M) offs[i] = bpre[blockIdx.x] + sm[t] - v;   // exclusive
}

// entry: x = src | (dst&15)<<20 ; y = norm
__global__ __launch_bounds__(256) void fill16_kernel(const int* __restrict__ src,
                                                     const int* __restrict__ dst,
                                                     const int* __restrict__ offs,
                                                     int* __restrict__ cur,
                                                     const float* __restrict__ dinv,
                                                     int2* __restrict__ csr, int e) {
    int i = blockIdx.x * 256 + threadIdx.x;
    if (i >= e) return;
    int s = src[i], d = dst[i];
    unsigned p = (unsigned)s >> PSH;
    size_t bin = (size_t)(d >> 4) * NP + p;
    int pos = offs[bin] + atomicAdd(&cur[bin], 1);
    csr[pos] = make_int2(s | ((d & 15) << 20), __float_as_int(dinv[s] * dinv[d]));
}

// ---------------- Aggregate: LDS dst-accumulators, partition-ordered edge stream ----------
// Block = 512 thr (8 waves); wave owns 16 dst rows (f32x2/lane in LDS = 8KB).
// Wave's edges are contiguous in csr, sorted by src-partition -> chip-wide sweep
// keeps the instantaneous gather footprint at ~1-2 partitions (2-4MB, cache-resident).

#define RMW(rk, nk, dk)                                              \
    {                                                                \
        float2 t = acc2[wbase + (dk)][lane];                         \
        t.x += bflo(rk) * (nk);                                      \
        t.y += bfhi(rk) * (nk);                                      \
        acc2[wbase + (dk)][lane] = t;                                \
    }

template <int POOL>
__global__ __launch_bounds__(512) void aggL_kernel(const unsigned* __restrict__ hlb,
                                                   const int* __restrict__ offs,
                                                   const int2* __restrict__ csr,
                                                   const float* __restrict__ dinv,
                                                   const float* __restrict__ bias,
                                                   void* __restrict__ outp,
                                                   const int* __restrict__ batch, int n) {
    __shared__ float2 acc2[128][64];                 // 64KB
    const int lane = threadIdx.x & 63;
    const int w = __builtin_amdgcn_readfirstlane(threadIdx.x >> 6);   // 0..7
    const int gw = blockIdx.x * 8 + w;
    const int wbase = w * 16;
    const float2 bv = ((const float2*)bias)[lane];

    #pragma unroll
    for (int dl = 0; dl < 16; dl++)
        acc2[wbase + dl][lane] = make_float2(0.0f, 0.0f);

    const int e0 = offs[gw * NP];
    const int e1 = offs[gw * NP + NP];
    int e = e0;
    int nb = (e1 - e0) >> 3;

    int2 c0, c1, c2, c3, c4, c5, c6, c7;
    if (nb > 0) {
        c0 = csr[e + 0]; c1 = csr[e + 1]; c2 = csr[e + 2]; c3 = csr[e + 3];
        c4 = csr[e + 4]; c5 = csr[e + 5]; c6 = csr[e + 6]; c7 = csr[e + 7];
    }
    for (int b = 0; b < nb; b++) {
        // issue 8 gathers (scalar base + lane)
        unsigned r0 = hlb[((size_t)(c0.x & 0xFFFFF) << 6) + lane];
        unsigned r1 = hlb[((size_t)(c1.x & 0xFFFFF) << 6) + lane];
        unsigned r2 = hlb[((size_t)(c2.x & 0xFFFFF) << 6) + lane];
        unsigned r3 = hlb[((size_t)(c3.x & 0xFFFFF) << 6) + lane];
        unsigned r4 = hlb[((size_t)(c4.x & 0xFFFFF) << 6) + lane];
        unsigned r5 = hlb[((size_t)(c5.x & 0xFFFFF) << 6) + lane];
        unsigned r6 = hlb[((size_t)(c6.x & 0xFFFFF) << 6) + lane];
        unsigned r7 = hlb[((size_t)(c7.x & 0xFFFFF) << 6) + lane];
        float n0 = __int_as_float(c0.y), n1 = __int_as_float(c1.y);
        float n2 = __int_as_float(c2.y), n3 = __int_as_float(c3.y);
        float n4 = __int_as_float(c4.y), n5 = __int_as_float(c5.y);
        float n6 = __int_as_float(c6.y), n7 = __int_as_float(c7.y);
        int d0 = (unsigned)c0.x >> 20, d1 = (unsigned)c1.x >> 20;
        int d2 = (unsigned)c2.x >> 20, d3 = (unsigned)c3.x >> 20;
        int d4 = (unsigned)c4.x >> 20, d5 = (unsigned)c5.x >> 20;
        int d6 = (unsigned)c6.x >> 20, d7 = (unsigned)c7.x >> 20;
        e += 8;
        if (b + 1 < nb) {   // prefetch next csr batch before consuming rows
            c0 = csr[e + 0]; c1 = csr[e + 1]; c2 = csr[e + 2]; c3 = csr[e + 3];
            c4 = csr[e + 4]; c5 = csr[e + 5]; c6 = csr[e + 6]; c7 = csr[e + 7];
        }
        // sequential RMWs (same-dst aliasing within batch is possible -> keep order)
        RMW(r0, n0, d0); RMW(r1, n1, d1); RMW(r2, n2, d2); RMW(r3, n3, d3);
        RMW(r4, n4, d4); RMW(r5, n5, d5); RMW(r6, n6, d6); RMW(r7, n7, d7);
    }
    for (; e < e1; e++) {
        int2 c = csr[e];
        unsigned r = hlb[((size_t)(c.x & 0xFFFFF) << 6) + lane];
        float nf = __int_as_float(c.y);
        int dl = (unsigned)c.x >> 20;
        RMW(r, nf, dl);
    }

    // epilogue: self loop + bias + relu (wave-exclusive dst range, no barrier)
    #pragma unroll
    for (int dl = 0; dl < 16; dl++) {
        int d = gw * 16 + dl;
        if (d < n) {
            float2 t = acc2[wbase + dl][lane];
            float di = dinv[d];
            float sw = di * di;
            unsigned s = hlb[((size_t)d << 6) + lane];
            float rx = fmaxf(t.x + bflo(s) * sw + bv.x, 0.0f);
            float ry = fmaxf(t.y + bfhi(s) * sw + bv.y, 0.0f);
            if (POOL) {
                int g = batch[d];
                float* out = (float*)outp;
                atomicMax((int*)&out[(size_t)g * F + 2 * lane + 0], __float_as_int(rx));
                atomicMax((int*)&out[(size_t)g * F + 2 * lane + 1], __float_as_int(ry));
            } else {
                unsigned lo = (unsigned)f32_to_bf16_rne(rx);
                unsigned hi = (unsigned)f32_to_bf16_rne(ry);
                ((unsigned*)outp)[((size_t)d << 6) + lane] = lo | (hi << 16);
            }
        }
    }
}

// ---------------- MLP head + log_softmax ----------------

__global__ __launch_bounds__(128) void mlp_kernel(const float* __restrict__ pooled,
                                                  const float* __restrict__ Wp1,
                                                  const float* __restrict__ bp1,
                                                  const float* __restrict__ Wp2,
                                                  const float* __restrict__ bp2,
                                                  float* __restrict__ out) {
    __shared__ float pl[F];
    __shared__ float s0[2], s1[2];
    int g = blockIdx.x, t = threadIdx.x;
    pl[t] = pooled[(size_t)g * F + t];
    __syncthreads();
    float a = bp1[t];
    #pragma unroll 8
    for (int k = 0; k < F; k++) a += pl[k] * Wp1[k * F + t];
    float p0 = a * Wp2[t * 2 + 0];
    float p1 = a * Wp2[t * 2 + 1];
    #pragma unroll
    for (int d = 32; d > 0; d >>= 1) {
        p0 += __shfl_down(p0, d, 64);
        p1 += __shfl_down(p1, d, 64);
    }
    if ((t & 63) == 0) { s0[t >> 6] = p0; s1[t >> 6] = p1; }
    __syncthreads();
    if (t == 0) {
        float l0 = s0[0] + s0[1] + bp2[0];
        float l1 = s1[0] + s1[1] + bp2[1];
        float m = fmaxf(l0, l1);
        float lse = m + logf(expf(l0 - m) + expf(l1 - m));
        out[g * 2 + 0] = l0 - lse;
        out[g * 2 + 1] = l1 - lse;
    }
}

// ---------------- launch ----------------

extern "C" void kernel_launch(void* const* d_in, const int* in_sizes, int n_in,
                              void* d_out, int out_size, void* d_ws, size_t ws_size,
                              hipStream_t stream) {
    const float* x    = (const float*)d_in[0];
    const int*   ei   = (const int*)d_in[1];
    const int*   batch= (const int*)d_in[2];
    const float* W1 = (const float*)d_in[3];  const float* b1 = (const float*)d_in[4];
    const float* W2 = (const float*)d_in[5];  const float* b2 = (const float*)d_in[6];
    const float* W3 = (const float*)d_in[7];  const float* b3 = (const float*)d_in[8];
    const float* Wp1= (const float*)d_in[9];  const float* bp1= (const float*)d_in[10];
    const float* Wp2= (const float*)d_in[11]; const float* bp2= (const float*)d_in[12];

    const int N = in_sizes[0] / F;
    const int E = in_sizes[1] / 2;
    const int G = out_size / 2;
    const int* srcp = ei;
    const int* dstp = ei + E;
    const int eb = (E + 255) / 256;
    const int nb = (N + 255) / 256;

    const int nblocks = (N + 127) / 128;         // aggL blocks (128 dst each)
    const size_t M = (size_t)nblocks * 8 * NP;   // bins
    const int nblkM = (int)((M + 255) / 256);

    char* w = (char*)d_ws;
    size_t off = 0;
    auto alloc = [&](size_t bytes) -> void* {
        void* p = w + off;
        off = (off + bytes + 255) & ~(size_t)255;
        return p;
    };
    unsigned short* xb   = (unsigned short*)alloc((size_t)N * F * 2);
    unsigned short* hlb  = (unsigned short*)alloc((size_t)N * F * 2);
    unsigned short* hab  = (unsigned short*)alloc((size_t)N * F * 2);
    unsigned short* Wt1  = (unsigned short*)alloc((size_t)F * F * 2);
    unsigned short* Wt2  = (unsigned short*)alloc((size_t)F * F * 2);
    unsigned short* Wt3  = (unsigned short*)alloc((size_t)F * F * 2);
    int*   cnt16  = (int*)alloc(M * 4);
    int*   cur16  = (int*)alloc(M * 4);
    int*   offs16 = (int*)alloc((M + 1) * 4);
    int*   bsum   = (int*)alloc((size_t)nblkM * 4);
    int*   bpre   = (int*)alloc((size_t)nblkM * 4);
    int*   cntd   = (int*)alloc((size_t)N * 4);
    float* dinv   = (float*)alloc((size_t)N * 4);
    int2*  csr16  = (int2*)alloc((size_t)E * 8);
    float* pooled = (float*)alloc((size_t)G * F * 4);

    hipMemsetAsync(cnt16, 0, M * 4, stream);
    hipMemsetAsync(cur16, 0, M * 4, stream);
    hipMemsetAsync(cntd,  0, (size_t)N * 4, stream);
    hipMemsetAsync(pooled, 0, (size_t)G * F * 4, stream);

    cvtx_kernel<<<2048, 256, 0, stream>>>((const float4*)x, (ushort4*)xb, (long)N * F / 4);
    cvtw_kernel<<<F, F, 0, stream>>>(W1, Wt1);
    cvtw_kernel<<<F, F, 0, stream>>>(W2, Wt2);
    cvtw_kernel<<<F, F, 0, stream>>>(W3, Wt3);

    count16_kernel<<<eb, 256, 0, stream>>>(srcp, dstp, cnt16, cntd, E);
    dinv_kernel<<<nb, 256, 0, stream>>>(cntd, dinv, N);
    scanA_kernel<<<nblkM, 256, 0, stream>>>(cnt16, bsum, (int)M);
    scanB_kernel<<<1, 1024, 0, stream>>>(bsum, bpre, offs16, nblkM, (int)M);
    scanC_kernel<<<nblkM, 256, 0, stream>>>(cnt16, bpre, offs16, (int)M);
    fill16_kernel<<<eb, 256, 0, stream>>>(srcp, dstp, offs16, cur16, dinv, csr16, E);

    const int gb = (N + 63) / 64;

    gemm_mfma<<<gb, 256, 0, stream>>>(xb, Wt1, hlb, N);
    aggL_kernel<0><<<nblocks, 512, 0, stream>>>((const unsigned*)hlb, offs16, csr16, dinv, b1, hab, nullptr, N);
    gemm_mfma<<<gb, 256, 0, stream>>>(hab, Wt2, hlb, N);
    aggL_kernel<0><<<nblocks, 512, 0, stream>>>((const unsigned*)hlb, offs16, csr16, dinv, b2, hab, nullptr, N);
    gemm_mfma<<<gb, 256, 0, stream>>>(hab, Wt3, hlb, N);
    aggL_kernel<1><<<nblocks, 512, 0, stream>>>((const unsigned*)hlb, offs16, csr16, dinv, b3, pooled, batch, N);

    mlp_kernel<<<G, 128, 0, stream>>>(pooled, Wp1, bp1, Wp2, bp2, (float*)d_out);
}

// Round 14
// 631.395 us; speedup vs baseline: 2.6201x; 1.0798x over previous
//
#include <hip/hip_runtime.h>

#define F 128
#define PSH 13            // src partition = s >> 13 (8192 nodes = 2MB bf16), p in [0,13)
#define NP 13
#define DPW 8             // dst rows per wave (32KB LDS / block of 8 waves)

typedef __attribute__((ext_vector_type(8))) short bf16x8;
typedef __attribute__((ext_vector_type(4))) float f32x4;

// ---------------- bf16 helpers ----------------

__device__ __forceinline__ unsigned short f32_to_bf16_rne(float x) {
    unsigned u = __float_as_uint(x);
    unsigned r = (u + 0x7fffu + ((u >> 16) & 1u)) >> 16;   // round to nearest even
    return (unsigned short)r;
}

__device__ __forceinline__ float bfhi(unsigned v) { return __uint_as_float(v & 0xffff0000u); }
__device__ __forceinline__ float bflo(unsigned v) { return __uint_as_float(v << 16); }

// ---------------- converts ----------------

__global__ __launch_bounds__(256) void cvtx_kernel(const float4* __restrict__ x4,
                                                   ushort4* __restrict__ xb4, long n4) {
    long stride = (long)gridDim.x * 256;
    for (long i = blockIdx.x * 256 + threadIdx.x; i < n4; i += stride) {
        float4 v = x4[i];
        ushort4 o;
        o.x = f32_to_bf16_rne(v.x);
        o.y = f32_to_bf16_rne(v.y);
        o.z = f32_to_bf16_rne(v.z);
        o.w = f32_to_bf16_rne(v.w);
        xb4[i] = o;
    }
}

__global__ __launch_bounds__(128) void cvtw_kernel(const float* __restrict__ W,
                                                   unsigned short* __restrict__ Wt) {
    int c = blockIdx.x, k = threadIdx.x;
    Wt[c * F + k] = f32_to_bf16_rne(W[k * F + c]);
}

// ---------------- MFMA GEMM ----------------

__global__ __launch_bounds__(256) void gemm_mfma(const unsigned short* __restrict__ hb,
                                                 const unsigned short* __restrict__ Wt,
                                                 unsigned short* __restrict__ outb, int n) {
    __shared__ unsigned short sm[4][16][F + 4];
    const int tid = threadIdx.x;
    const int w = tid >> 6, lane = tid & 63;
    const int r = lane & 15, kg = lane >> 4;
    const long base = (long)blockIdx.x * 64 + w * 16;

    int arow = (int)(base + r);
    if (arow >= n) arow = n - 1;
    const bf16x8* __restrict__ arowp = (const bf16x8*)(hb + (size_t)arow * F);

    f32x4 acc[8] = {};
    #pragma unroll
    for (int c = 0; c < 4; c++) {
        bf16x8 a = arowp[c * 4 + kg];
        #pragma unroll
        for (int t = 0; t < 8; t++) {
            bf16x8 b = *(const bf16x8*)(Wt + (size_t)(t * 16 + r) * F + c * 32 + kg * 8);
            acc[t] = __builtin_amdgcn_mfma_f32_16x16x32_bf16(a, b, acc[t], 0, 0, 0);
        }
    }

    #pragma unroll
    for (int t = 0; t < 8; t++)
        #pragma unroll
        for (int j = 0; j < 4; j++)
            sm[w][kg * 4 + j][t * 16 + r] = f32_to_bf16_rne(acc[t][j]);
    #pragma unroll
    for (int it = 0; it < 4; it++) {
        int row = it * 4 + kg;
        long grow = base + row;
        if (grow < n) {
            uint4 v = *(uint4*)&sm[w][row][r * 8];
            *(uint4*)(outb + (size_t)grow * F + r * 8) = v;
        }
    }
}

// ---------------- build: edges binned by (wave-group gw = d>>3, src partition) ----------

__global__ __launch_bounds__(256) void count16_kernel(const int* __restrict__ src,
                                                      const int* __restrict__ dst,
                                                      int* __restrict__ cnt,
                                                      int* __restrict__ cntd, int e) {
    int i = blockIdx.x * 256 + threadIdx.x;
    if (i >= e) return;
    int s = src[i], d = dst[i];
    unsigned p = (unsigned)s >> PSH;
    atomicAdd(&cnt[(size_t)(d >> 3) * NP + p], 1);
    atomicAdd(&cntd[d], 1);
}

__global__ __launch_bounds__(256) void dinv_kernel(const int* __restrict__ cnt,
                                                   float* __restrict__ dinv, int n) {
    int i = blockIdx.x * 256 + threadIdx.x;
    if (i < n) dinv[i] = rsqrtf((float)(cnt[i] + 1));
}

// 3-phase coalesced scan over M elements
__global__ __launch_bounds__(256) void scanA_kernel(const int* __restrict__ cnt,
                                                    int* __restrict__ bsum, int M) {
    __shared__ int sm[256];
    int t = threadIdx.x;
    int i = blockIdx.x * 256 + t;
    int v = (i < M) ? cnt[i] : 0;
    sm[t] = v;
    __syncthreads();
    for (int d = 128; d > 0; d >>= 1) {
        if (t < d) sm[t] += sm[t + d];
        __syncthreads();
    }
    if (t == 0) bsum[blockIdx.x] = sm[0];
}

__global__ __launch_bounds__(1024) void scanB_kernel(const int* __restrict__ bsum,
                                                     int* __restrict__ bpre,
                                                     int* __restrict__ offs, int nb, int M) {
    __shared__ int sm[1024];
    int t = threadIdx.x;
    int chunk = (nb + 1023) >> 10;
    int b = t * chunk;
    int e = b + chunk; if (e > nb) e = nb;
    int s = 0;
    for (int i = b; i < e; i++) s += bsum[i];
    sm[t] = s;
    __syncthreads();
    for (int d = 1; d < 1024; d <<= 1) {
        int v = 0;
        if (t >= d) v = sm[t - d];
        __syncthreads();
        if (t >= d) sm[t] += v;
        __syncthreads();
    }
    int run = (t == 0) ? 0 : sm[t - 1];
    for (int i = b; i < e; i++) { bpre[i] = run; run += bsum[i]; }
    if (t == 1023) offs[M] = sm[1023];
}

__global__ __launch_bounds__(256) void scanC_kernel(const int* __restrict__ cnt,
                                                    const int* __restrict__ bpre,
                                                    int* __restrict__ offs, int M) {
    __shared__ int sm[256];
    int t = threadIdx.x;
    int i = blockIdx.x * 256 + t;
    int v = (i < M) ? cnt[i] : 0;
    sm[t] = v;
    __syncthreads();
    for (int d = 1; d < 256; d <<= 1) {
        int u = 0;
        if (t >= d) u = sm[t - d];
        __syncthreads();
        if (t >= d) sm[t] += u;
        __syncthreads();
    }
    if (i < M) offs[i] = bpre[blockIdx.x] + sm[t] - v;   // exclusive
}

// entry: x = src | (dst&7)<<20 ; y = norm
__global__ __launch_bounds__(256) void fill16_kernel(const int* __restrict__ src,
                                                     const int* __restrict__ dst,
                                                     const int* __restrict__ offs,
                                                     int* __restrict__ cur,
                                                     const float* __restrict__ dinv,
                                                     int2* __restrict__ csr, int e) {
    int i = blockIdx.x * 256 + threadIdx.x;
    if (i >= e) return;
    int s = src[i], d = dst[i];
    unsigned p = (unsigned)s >> PSH;
    size_t bin = (size_t)(d >> 3) * NP + p;
    int pos = offs[bin] + atomicAdd(&cur[bin], 1);
    csr[pos] = make_int2(s | ((d & 7) << 20), __float_as_int(dinv[s] * dinv[d]));
}

// ---------------- Aggregate: 32KB LDS dst-accumulators, partition-ordered stream ----------
// Block = 512 thr (8 waves); wave owns 8 dst rows (f32x2/lane in LDS = 4KB).
// 4 blocks/CU -> occupancy ~100% while keeping the partition-ordered sweep.

#define RMW(rk, nk, dk)                                              \
    {                                                                \
        float2 t = acc2[wbase + (dk)][lane];                         \
        t.x += bflo(rk) * (nk);                                      \
        t.y += bfhi(rk) * (nk);                                      \
        acc2[wbase + (dk)][lane] = t;                                \
    }

template <int POOL>
__global__ __launch_bounds__(512) void aggL_kernel(const unsigned* __restrict__ hlb,
                                                   const int* __restrict__ offs,
                                                   const int2* __restrict__ csr,
                                                   const float* __restrict__ dinv,
                                                   const float* __restrict__ bias,
                                                   void* __restrict__ outp,
                                                   const int* __restrict__ batch, int n) {
    __shared__ float2 acc2[64][64];                  // 32KB
    const int lane = threadIdx.x & 63;
    const int w = __builtin_amdgcn_readfirstlane(threadIdx.x >> 6);   // 0..7
    const int gw = blockIdx.x * 8 + w;
    const int wbase = w * DPW;
    const float2 bv = ((const float2*)bias)[lane];

    #pragma unroll
    for (int dl = 0; dl < DPW; dl++)
        acc2[wbase + dl][lane] = make_float2(0.0f, 0.0f);

    const int e0 = offs[gw * NP];
    const int e1 = offs[gw * NP + NP];
    int e = e0;
    int nb = (e1 - e0) >> 3;

    int2 c0, c1, c2, c3, c4, c5, c6, c7;
    if (nb > 0) {
        c0 = csr[e + 0]; c1 = csr[e + 1]; c2 = csr[e + 2]; c3 = csr[e + 3];
        c4 = csr[e + 4]; c5 = csr[e + 5]; c6 = csr[e + 6]; c7 = csr[e + 7];
    }
    for (int b = 0; b < nb; b++) {
        unsigned r0 = hlb[((size_t)(c0.x & 0xFFFFF) << 6) + lane];
        unsigned r1 = hlb[((size_t)(c1.x & 0xFFFFF) << 6) + lane];
        unsigned r2 = hlb[((size_t)(c2.x & 0xFFFFF) << 6) + lane];
        unsigned r3 = hlb[((size_t)(c3.x & 0xFFFFF) << 6) + lane];
        unsigned r4 = hlb[((size_t)(c4.x & 0xFFFFF) << 6) + lane];
        unsigned r5 = hlb[((size_t)(c5.x & 0xFFFFF) << 6) + lane];
        unsigned r6 = hlb[((size_t)(c6.x & 0xFFFFF) << 6) + lane];
        unsigned r7 = hlb[((size_t)(c7.x & 0xFFFFF) << 6) + lane];
        float n0 = __int_as_float(c0.y), n1 = __int_as_float(c1.y);
        float n2 = __int_as_float(c2.y), n3 = __int_as_float(c3.y);
        float n4 = __int_as_float(c4.y), n5 = __int_as_float(c5.y);
        float n6 = __int_as_float(c6.y), n7 = __int_as_float(c7.y);
        int d0 = (unsigned)c0.x >> 20, d1 = (unsigned)c1.x >> 20;
        int d2 = (unsigned)c2.x >> 20, d3 = (unsigned)c3.x >> 20;
        int d4 = (unsigned)c4.x >> 20, d5 = (unsigned)c5.x >> 20;
        int d6 = (unsigned)c6.x >> 20, d7 = (unsigned)c7.x >> 20;
        e += 8;
        if (b + 1 < nb) {
            c0 = csr[e + 0]; c1 = csr[e + 1]; c2 = csr[e + 2]; c3 = csr[e + 3];
            c4 = csr[e + 4]; c5 = csr[e + 5]; c6 = csr[e + 6]; c7 = csr[e + 7];
        }
        RMW(r0, n0, d0); RMW(r1, n1, d1); RMW(r2, n2, d2); RMW(r3, n3, d3);
        RMW(r4, n4, d4); RMW(r5, n5, d5); RMW(r6, n6, d6); RMW(r7, n7, d7);
    }
    for (; e < e1; e++) {
        int2 c = csr[e];
        unsigned r = hlb[((size_t)(c.x & 0xFFFFF) << 6) + lane];
        float nf = __int_as_float(c.y);
        int dl = (unsigned)c.x >> 20;
        RMW(r, nf, dl);
    }

    // epilogue: self loop + bias + relu (wave-exclusive dst range, no barrier)
    #pragma unroll
    for (int dl = 0; dl < DPW; dl++) {
        int d = gw * DPW + dl;
        if (d < n) {
            float2 t = acc2[wbase + dl][lane];
            float di = dinv[d];
            float sw = di * di;
            unsigned s = hlb[((size_t)d << 6) + lane];
            float rx = fmaxf(t.x + bflo(s) * sw + bv.x, 0.0f);
            float ry = fmaxf(t.y + bfhi(s) * sw + bv.y, 0.0f);
            if (POOL) {
                int g = batch[d];
                float* out = (float*)outp;
                atomicMax((int*)&out[(size_t)g * F + 2 * lane + 0], __float_as_int(rx));
                atomicMax((int*)&out[(size_t)g * F + 2 * lane + 1], __float_as_int(ry));
            } else {
                unsigned lo = (unsigned)f32_to_bf16_rne(rx);
                unsigned hi = (unsigned)f32_to_bf16_rne(ry);
                ((unsigned*)outp)[((size_t)d << 6) + lane] = lo | (hi << 16);
            }
        }
    }
}

// ---------------- MLP head + log_softmax ----------------

__global__ __launch_bounds__(128) void mlp_kernel(const float* __restrict__ pooled,
                                                  const float* __restrict__ Wp1,
                                                  const float* __restrict__ bp1,
                                                  const float* __restrict__ Wp2,
                                                  const float* __restrict__ bp2,
                                                  float* __restrict__ out) {
    __shared__ float pl[F];
    __shared__ float s0[2], s1[2];
    int g = blockIdx.x, t = threadIdx.x;
    pl[t] = pooled[(size_t)g * F + t];
    __syncthreads();
    float a = bp1[t];
    #pragma unroll 8
    for (int k = 0; k < F; k++) a += pl[k] * Wp1[k * F + t];
    float p0 = a * Wp2[t * 2 + 0];
    float p1 = a * Wp2[t * 2 + 1];
    #pragma unroll
    for (int d = 32; d > 0; d >>= 1) {
        p0 += __shfl_down(p0, d, 64);
        p1 += __shfl_down(p1, d, 64);
    }
    if ((t & 63) == 0) { s0[t >> 6] = p0; s1[t >> 6] = p1; }
    __syncthreads();
    if (t == 0) {
        float l0 = s0[0] + s0[1] + bp2[0];
        float l1 = s1[0] + s1[1] + bp2[1];
        float m = fmaxf(l0, l1);
        float lse = m + logf(expf(l0 - m) + expf(l1 - m));
        out[g * 2 + 0] = l0 - lse;
        out[g * 2 + 1] = l1 - lse;
    }
}

// ---------------- launch ----------------

extern "C" void kernel_launch(void* const* d_in, const int* in_sizes, int n_in,
                              void* d_out, int out_size, void* d_ws, size_t ws_size,
                              hipStream_t stream) {
    const float* x    = (const float*)d_in[0];
    const int*   ei   = (const int*)d_in[1];
    const int*   batch= (const int*)d_in[2];
    const float* W1 = (const float*)d_in[3];  const float* b1 = (const float*)d_in[4];
    const float* W2 = (const float*)d_in[5];  const float* b2 = (const float*)d_in[6];
    const float* W3 = (const float*)d_in[7];  const float* b3 = (const float*)d_in[8];
    const float* Wp1= (const float*)d_in[9];  const float* bp1= (const float*)d_in[10];
    const float* Wp2= (const float*)d_in[11]; const float* bp2= (const float*)d_in[12];

    const int N = in_sizes[0] / F;
    const int E = in_sizes[1] / 2;
    const int G = out_size / 2;
    const int* srcp = ei;
    const int* dstp = ei + E;
    const int eb = (E + 255) / 256;
    const int nb = (N + 255) / 256;

    const int nblocks = (N + 63) / 64;           // aggL blocks (64 dst each)
    const size_t M = (size_t)nblocks * 8 * NP;   // bins
    const int nblkM = (int)((M + 255) / 256);

    char* w = (char*)d_ws;
    size_t off = 0;
    auto alloc = [&](size_t bytes) -> void* {
        void* p = w + off;
        off = (off + bytes + 255) & ~(size_t)255;
        return p;
    };
    unsigned short* xb   = (unsigned short*)alloc((size_t)N * F * 2);
    unsigned short* hlb  = (unsigned short*)alloc((size_t)N * F * 2);
    unsigned short* hab  = (unsigned short*)alloc((size_t)N * F * 2);
    unsigned short* Wt1  = (unsigned short*)alloc((size_t)F * F * 2);
    unsigned short* Wt2  = (unsigned short*)alloc((size_t)F * F * 2);
    unsigned short* Wt3  = (unsigned short*)alloc((size_t)F * F * 2);
    int*   cnt16  = (int*)alloc(M * 4);
    int*   cur16  = (int*)alloc(M * 4);
    int*   offs16 = (int*)alloc((M + 1) * 4);
    int*   bsum   = (int*)alloc((size_t)nblkM * 4);
    int*   bpre   = (int*)alloc((size_t)nblkM * 4);
    int*   cntd   = (int*)alloc((size_t)N * 4);
    float* dinv   = (float*)alloc((size_t)N * 4);
    int2*  csr16  = (int2*)alloc((size_t)E * 8);
    float* pooled = (float*)alloc((size_t)G * F * 4);

    hipMemsetAsync(cnt16, 0, M * 4, stream);
    hipMemsetAsync(cur16, 0, M * 4, stream);
    hipMemsetAsync(cntd,  0, (size_t)N * 4, stream);
    hipMemsetAsync(pooled, 0, (size_t)G * F * 4, stream);

    cvtx_kernel<<<2048, 256, 0, stream>>>((const float4*)x, (ushort4*)xb, (long)N * F / 4);
    cvtw_kernel<<<F, F, 0, stream>>>(W1, Wt1);
    cvtw_kernel<<<F, F, 0, stream>>>(W2, Wt2);
    cvtw_kernel<<<F, F, 0, stream>>>(W3, Wt3);

    count16_kernel<<<eb, 256, 0, stream>>>(srcp, dstp, cnt16, cntd, E);
    dinv_kernel<<<nb, 256, 0, stream>>>(cntd, dinv, N);
    scanA_kernel<<<nblkM, 256, 0, stream>>>(cnt16, bsum, (int)M);
    scanB_kernel<<<1, 1024, 0, stream>>>(bsum, bpre, offs16, nblkM, (int)M);
    scanC_kernel<<<nblkM, 256, 0, stream>>>(cnt16, bpre, offs16, (int)M);
    fill16_kernel<<<eb, 256, 0, stream>>>(srcp, dstp, offs16, cur16, dinv, csr16, E);

    const int gb = (N + 63) / 64;

    gemm_mfma<<<gb, 256, 0, stream>>>(xb, Wt1, hlb, N);
    aggL_kernel<0><<<nblocks, 512, 0, stream>>>((const unsigned*)hlb, offs16, csr16, dinv, b1, hab, nullptr, N);
    gemm_mfma<<<gb, 256, 0, stream>>>(hab, Wt2, hlb, N);
    aggL_kernel<0><<<nblocks, 512, 0, stream>>>((const unsigned*)hlb, offs16, csr16, dinv, b2, hab, nullptr, N);
    gemm_mfma<<<gb, 256, 0, stream>>>(hab, Wt3, hlb, N);
    aggL_kernel<1><<<nblocks, 512, 0, stream>>>((const unsigned*)hlb, offs16, csr16, dinv, b3, pooled, batch, N);

    mlp_kernel<<<G, 128, 0, stream>>>(pooled, Wp1, bp1, Wp2, bp2, (float*)d_out);
}